// Round 1
// baseline (1786.407 us; speedup 1.0000x reference)
//
#include <hip/hip_runtime.h>
#include <math.h>

#define N_NODES 100000
#define E_EDGES 1600000
#define E_TOT   (E_EDGES + N_NODES)
#define G_GRAPHS 64
#define IN_DIM 256
#define HID 64
#define HEADS 4
#define D1 256            // HEADS*HID
#define NEG_SLOPE 0.2f
#define SCAN_B 1024

// ---------------- generic fp32 tiled GEMM: C[M,Nc] = A[M,K] @ B[K,Nc] ----------------
// tile 64x64x16, 256 threads, 4x4 microtile
__global__ __launch_bounds__(256) void gemm_tiled(const float* __restrict__ A,
                                                  const float* __restrict__ B,
                                                  float* __restrict__ C,
                                                  int M, int K, int Nc)
{
    __shared__ float AsT[16][68];   // [k][m], padded to 68 (16B-aligned rows)
    __shared__ float Bs[16][68];    // [k][n]
    const int tid = threadIdx.x;
    const int tx = tid & 15, ty = tid >> 4;
    const int bm = blockIdx.y * 64, bn = blockIdx.x * 64;
    float acc[4][4] = {};

    const int ar  = tid >> 2;          // 0..63 : A row within tile
    const int akq = (tid & 3) * 4;     // 0,4,8,12 : k quad
    const int bkr = tid >> 4;          // 0..15 : B k row
    const int bnq = (tid & 15) * 4;    // 0..60 : B col quad

    for (int k0 = 0; k0 < K; k0 += 16) {
        float4 av = make_float4(0.f, 0.f, 0.f, 0.f);
        int m = bm + ar;
        if (m < M) av = *(const float4*)(A + (size_t)m * K + k0 + akq);
        AsT[akq + 0][ar] = av.x;
        AsT[akq + 1][ar] = av.y;
        AsT[akq + 2][ar] = av.z;
        AsT[akq + 3][ar] = av.w;
        float4 bv = *(const float4*)(B + (size_t)(k0 + bkr) * Nc + bn + bnq);
        *(float4*)(&Bs[bkr][bnq]) = bv;
        __syncthreads();
#pragma unroll
        for (int k = 0; k < 16; ++k) {
            float4 a4 = *(const float4*)(&AsT[k][ty * 4]);
            float4 b4 = *(const float4*)(&Bs[k][tx * 4]);
            acc[0][0] += a4.x * b4.x; acc[0][1] += a4.x * b4.y; acc[0][2] += a4.x * b4.z; acc[0][3] += a4.x * b4.w;
            acc[1][0] += a4.y * b4.x; acc[1][1] += a4.y * b4.y; acc[1][2] += a4.y * b4.z; acc[1][3] += a4.y * b4.w;
            acc[2][0] += a4.z * b4.x; acc[2][1] += a4.z * b4.y; acc[2][2] += a4.z * b4.z; acc[2][3] += a4.z * b4.w;
            acc[3][0] += a4.w * b4.x; acc[3][1] += a4.w * b4.y; acc[3][2] += a4.w * b4.z; acc[3][3] += a4.w * b4.w;
        }
        __syncthreads();
    }
#pragma unroll
    for (int i = 0; i < 4; ++i) {
        int m = bm + ty * 4 + i;
        if (m < M) {
#pragma unroll
            for (int j = 0; j < 4; ++j)
                C[(size_t)m * Nc + bn + tx * 4 + j] = acc[i][j];
        }
    }
}

// ---------------- attention scalar products, layer 1: a_src/a_dst [N,4] ----------------
__global__ __launch_bounds__(256) void att1_kernel(const float* __restrict__ h1,
                                                   const float* __restrict__ att_src,
                                                   const float* __restrict__ att_dst,
                                                   float* __restrict__ a_src,
                                                   float* __restrict__ a_dst)
{
    const int wave = threadIdx.x >> 6, lane = threadIdx.x & 63;
    const int n = blockIdx.x * 4 + wave;
    if (n >= N_NODES) return;
    const int h = lane >> 4;
    float4 v = *(const float4*)(h1 + (size_t)n * D1 + lane * 4);
    float4 s4 = *(const float4*)(att_src + lane * 4);   // lane*4 == h*64 + (lane&15)*4
    float4 d4 = *(const float4*)(att_dst + lane * 4);
    float ps = v.x * s4.x + v.y * s4.y + v.z * s4.z + v.w * s4.w;
    float pd = v.x * d4.x + v.y * d4.y + v.z * d4.z + v.w * d4.w;
#pragma unroll
    for (int o = 1; o < 16; o <<= 1) { ps += __shfl_xor(ps, o); pd += __shfl_xor(pd, o); }
    if ((lane & 15) == 0) { a_src[n * 4 + h] = ps; a_dst[n * 4 + h] = pd; }
}

// ---------------- attention scalar products, layer 2: a_src/a_dst [N] ----------------
__global__ __launch_bounds__(256) void att2_kernel(const float* __restrict__ h2,
                                                   const float* __restrict__ att_src,
                                                   const float* __restrict__ att_dst,
                                                   float* __restrict__ a_src,
                                                   float* __restrict__ a_dst)
{
    const int wave = threadIdx.x >> 6, lane = threadIdx.x & 63;
    const int n = blockIdx.x * 4 + wave;
    if (n >= N_NODES) return;
    float v = h2[(size_t)n * HID + lane];
    float ps = v * att_src[lane];
    float pd = v * att_dst[lane];
#pragma unroll
    for (int o = 1; o < 64; o <<= 1) { ps += __shfl_xor(ps, o); pd += __shfl_xor(pd, o); }
    if (lane == 0) { a_src[n] = ps; a_dst[n] = pd; }
}

// ---------------- CSR build: histogram, scan, scatter ----------------
__global__ void edge_hist(const int* __restrict__ ei, int* __restrict__ deg)
{
    for (int e = blockIdx.x * blockDim.x + threadIdx.x; e < E_TOT; e += gridDim.x * blockDim.x) {
        int d = (e < E_EDGES) ? ei[E_EDGES + e] : (e - E_EDGES);
        atomicAdd(&deg[d], 1);
    }
}

__global__ __launch_bounds__(SCAN_B) void scan_block(const int* __restrict__ deg,
                                                     int* __restrict__ incl,
                                                     int* __restrict__ bsum, int n)
{
    __shared__ int s[SCAN_B];
    int i = blockIdx.x * SCAN_B + threadIdx.x;
    int v = (i < n) ? deg[i] : 0;
    s[threadIdx.x] = v;
    __syncthreads();
    for (int off = 1; off < SCAN_B; off <<= 1) {
        int t = (threadIdx.x >= off) ? s[threadIdx.x - off] : 0;
        __syncthreads();
        s[threadIdx.x] += t;
        __syncthreads();
    }
    if (i < n) incl[i] = s[threadIdx.x];
    if (threadIdx.x == SCAN_B - 1) bsum[blockIdx.x] = s[SCAN_B - 1];
}

__global__ void scan_bsum(const int* __restrict__ bsum, int* __restrict__ bex, int nb)
{
    if (threadIdx.x == 0 && blockIdx.x == 0) {
        int run = 0;
        for (int b = 0; b < nb; ++b) { bex[b] = run; run += bsum[b]; }
    }
}

__global__ void finalize_off(const int* __restrict__ deg, const int* __restrict__ incl,
                             const int* __restrict__ bex, int* __restrict__ off,
                             int* __restrict__ cursor, int n)
{
    int i = blockIdx.x * blockDim.x + threadIdx.x;
    if (i < n) { off[i] = incl[i] - deg[i] + bex[i / SCAN_B]; cursor[i] = 0; }
}

__global__ void edge_scatter(const int* __restrict__ ei, const int* __restrict__ off,
                             int* __restrict__ cursor, int* __restrict__ csr_src)
{
    for (int e = blockIdx.x * blockDim.x + threadIdx.x; e < E_TOT; e += gridDim.x * blockDim.x) {
        int s = (e < E_EDGES) ? ei[e] : (e - E_EDGES);
        int d = (e < E_EDGES) ? ei[E_EDGES + e] : (e - E_EDGES);
        int slot = off[d] + atomicAdd(&cursor[d], 1);
        csr_src[slot] = s;
    }
}

// ---------------- layer-1 aggregation: wave per node, fused softmax-norm + b1 + ELU ----------------
__global__ __launch_bounds__(256) void agg1_kernel(const float* __restrict__ h1,
                                                   const int* __restrict__ csr_src,
                                                   const int* __restrict__ off,
                                                   const int* __restrict__ deg,
                                                   const float* __restrict__ a_src,
                                                   const float* __restrict__ a_dst,
                                                   const float* __restrict__ b1,
                                                   float* __restrict__ hE)
{
    const int wave = threadIdx.x >> 6, lane = threadIdx.x & 63;
    const int n = blockIdx.x * 4 + wave;
    if (n >= N_NODES) return;
    const int h = lane >> 4;
    const float adn = a_dst[n * 4 + h];
    const int st = off[n], cnt = deg[n];
    float4 acc = make_float4(0.f, 0.f, 0.f, 0.f);
    float dsum = 0.f;
    for (int j = 0; j < cnt; ++j) {
        int s = csr_src[st + j];
        float al = a_src[s * 4 + h] + adn;
        al = (al > 0.f) ? al : NEG_SLOPE * al;
        float ex = expf(al);
        dsum += ex;
        float4 v = *(const float4*)(h1 + (size_t)s * D1 + lane * 4);
        acc.x += ex * v.x; acc.y += ex * v.y; acc.z += ex * v.z; acc.w += ex * v.w;
    }
    const float inv = 1.f / (dsum + 1e-16f);
    float4 bb = *(const float4*)(b1 + lane * 4);
    float4 o;
    o.x = acc.x * inv + bb.x;
    o.y = acc.y * inv + bb.y;
    o.z = acc.z * inv + bb.z;
    o.w = acc.w * inv + bb.w;
    o.x = (o.x > 0.f) ? o.x : expm1f(o.x);
    o.y = (o.y > 0.f) ? o.y : expm1f(o.y);
    o.z = (o.z > 0.f) ? o.z : expm1f(o.z);
    o.w = (o.w > 0.f) ? o.w : expm1f(o.w);
    *(float4*)(hE + (size_t)n * D1 + lane * 4) = o;
}

// ---------------- layer-2 aggregation + fused mean-pool scatter ----------------
__global__ __launch_bounds__(256) void agg2_pool_kernel(const float* __restrict__ h2,
                                                        const int* __restrict__ csr_src,
                                                        const int* __restrict__ off,
                                                        const int* __restrict__ deg,
                                                        const float* __restrict__ a_src,
                                                        const float* __restrict__ a_dst,
                                                        const float* __restrict__ b2,
                                                        const int* __restrict__ batch,
                                                        float* __restrict__ pool,
                                                        float* __restrict__ cntg)
{
    const int wave = threadIdx.x >> 6, lane = threadIdx.x & 63;
    const int n = blockIdx.x * 4 + wave;
    if (n >= N_NODES) return;
    const float adn = a_dst[n];
    const int st = off[n], cnt = deg[n];
    float acc = 0.f, dsum = 0.f;
    for (int j = 0; j < cnt; ++j) {
        int s = csr_src[st + j];
        float al = a_src[s] + adn;
        al = (al > 0.f) ? al : NEG_SLOPE * al;
        float ex = expf(al);
        dsum += ex;
        acc += ex * h2[(size_t)s * HID + lane];
    }
    float val = acc / (dsum + 1e-16f) + b2[lane];
    int g = batch[n];
#if defined(__gfx950__) || defined(__AMDGCN__)
    unsafeAtomicAdd(&pool[g * HID + lane], val);
    if (lane == 0) unsafeAtomicAdd(&cntg[g], 1.0f);
#else
    atomicAdd(&pool[g * HID + lane], val);
    if (lane == 0) atomicAdd(&cntg[g], 1.0f);
#endif
}

// ---------------- head: mean, relu MLP, logits ----------------
__global__ void head_kernel(const float* __restrict__ pool, const float* __restrict__ cntg,
                            const float* __restrict__ W3, const float* __restrict__ b3,
                            const float* __restrict__ W4, const float* __restrict__ b4,
                            float* __restrict__ out)
{
    int g = threadIdx.x;
    if (g >= G_GRAPHS) return;
    float invc = 1.f / fmaxf(cntg[g], 1.f);
    float emb[HID];
#pragma unroll
    for (int k = 0; k < HID; ++k) emb[k] = pool[g * HID + k] * invc;
    float z[32];
    for (int j = 0; j < 32; ++j) {
        float s = b3[j];
        for (int k = 0; k < HID; ++k) s += emb[k] * W3[k * 32 + j];
        z[j] = fmaxf(s, 0.f);
    }
    for (int d = 0; d < 2; ++d) {
        float s = b4[d];
        for (int j = 0; j < 32; ++j) s += z[j] * W4[j * 2 + d];
        out[g * 2 + d] = s;
    }
}

extern "C" void kernel_launch(void* const* d_in, const int* in_sizes, int n_in,
                              void* d_out, int out_size, void* d_ws, size_t ws_size,
                              hipStream_t stream)
{
    const float* x     = (const float*)d_in[0];
    const int*   ei    = (const int*)d_in[1];
    const int*   batch = (const int*)d_in[2];
    const float* W1    = (const float*)d_in[3];
    const float* as1w  = (const float*)d_in[4];
    const float* ad1w  = (const float*)d_in[5];
    const float* b1    = (const float*)d_in[6];
    const float* W2    = (const float*)d_in[7];
    const float* as2w  = (const float*)d_in[8];
    const float* ad2w  = (const float*)d_in[9];
    const float* b2    = (const float*)d_in[10];
    const float* W3    = (const float*)d_in[11];
    const float* b3    = (const float*)d_in[12];
    const float* W4    = (const float*)d_in[13];
    const float* b4    = (const float*)d_in[14];
    float* out = (float*)d_out;

    char* ws = (char*)d_ws;
    size_t o = 0;
    auto alloc = [&](size_t bytes) -> void* {
        void* p = ws + o;
        o += (bytes + 255) & ~(size_t)255;
        return p;
    };
    float* h1   = (float*)alloc((size_t)N_NODES * D1 * 4);   // x@W1
    float* hE   = (float*)alloc((size_t)N_NODES * D1 * 4);   // elu(agg1 + b1)
    float* h2   = h1;                                        // alias: h1 dead after agg1
    float* a_s1 = (float*)alloc((size_t)N_NODES * 4 * 4);
    float* a_d1 = (float*)alloc((size_t)N_NODES * 4 * 4);
    float* a_s2 = (float*)alloc((size_t)N_NODES * 4);
    float* a_d2 = (float*)alloc((size_t)N_NODES * 4);
    int*   deg    = (int*)alloc((size_t)N_NODES * 4);
    int*   incl   = (int*)alloc((size_t)N_NODES * 4);
    int*   offv   = (int*)alloc((size_t)N_NODES * 4);
    int*   cursor = (int*)alloc((size_t)N_NODES * 4);
    int*   bsum   = (int*)alloc(128 * 4);
    int*   bex    = (int*)alloc(128 * 4);
    int*   csr    = (int*)alloc((size_t)E_TOT * 4);
    float* pool   = (float*)alloc((size_t)G_GRAPHS * HID * 4);
    float* cntg   = (float*)alloc((size_t)G_GRAPHS * 4);

    hipMemsetAsync(deg, 0, (size_t)N_NODES * 4, stream);
    hipMemsetAsync(pool, 0, (size_t)G_GRAPHS * HID * 4, stream);
    hipMemsetAsync(cntg, 0, (size_t)G_GRAPHS * 4, stream);

    const int nblk_nodes = (N_NODES + 3) / 4;          // 4 waves/block, 1 node/wave
    const int nscan = (N_NODES + SCAN_B - 1) / SCAN_B; // 98

    // GEMM1: h1 = x @ W1  [100000,256]x[256,256]
    gemm_tiled<<<dim3(D1 / 64, (N_NODES + 63) / 64), 256, 0, stream>>>(x, W1, h1, N_NODES, IN_DIM, D1);
    att1_kernel<<<nblk_nodes, 256, 0, stream>>>(h1, as1w, ad1w, a_s1, a_d1);

    // CSR build (shared by both layers)
    edge_hist<<<4096, 256, 0, stream>>>(ei, deg);
    scan_block<<<nscan, SCAN_B, 0, stream>>>(deg, incl, bsum, N_NODES);
    scan_bsum<<<1, 64, 0, stream>>>(bsum, bex, nscan);
    finalize_off<<<(N_NODES + 255) / 256, 256, 0, stream>>>(deg, incl, bex, offv, cursor, N_NODES);
    edge_scatter<<<4096, 256, 0, stream>>>(ei, offv, cursor, csr);

    // layer-1 gather-aggregate, fused softmax + b1 + ELU
    agg1_kernel<<<nblk_nodes, 256, 0, stream>>>(h1, csr, offv, deg, a_s1, a_d1, b1, hE);

    // GEMM2: h2 = hE @ W2  [100000,256]x[256,64]
    gemm_tiled<<<dim3(HID / 64, (N_NODES + 63) / 64), 256, 0, stream>>>(hE, W2, h2, N_NODES, D1, HID);
    att2_kernel<<<nblk_nodes, 256, 0, stream>>>(h2, as2w, ad2w, a_s2, a_d2);

    // layer-2 gather-aggregate + fused mean-pool scatter
    agg2_pool_kernel<<<nblk_nodes, 256, 0, stream>>>(h2, csr, offv, deg, a_s2, a_d2, b2, batch, pool, cntg);

    // head MLP
    head_kernel<<<1, 64, 0, stream>>>(pool, cntg, W3, b3, W4, b4, out);
}

// Round 2
// 1040.928 us; speedup vs baseline: 1.7162x; 1.7162x over previous
//
#include <hip/hip_runtime.h>
#include <math.h>

#define N_NODES 100000
#define E_EDGES 1600000
#define E_TOT   (E_EDGES + N_NODES)
#define G_GRAPHS 64
#define IN_DIM 256
#define HID 64
#define HEADS 4
#define D1 256            // HEADS*HID
#define NEG_SLOPE 0.2f
#define SCAN_B 1024
#define CHUNK2 16         // nodes per wave in agg2 (register pool accumulation)

// ---------------- generic fp32 tiled GEMM: C[M,Nc] = A[M,K] @ B[K,Nc] ----------------
// tile 64x64x16, 256 threads, 4x4 microtile
__global__ __launch_bounds__(256) void gemm_tiled(const float* __restrict__ A,
                                                  const float* __restrict__ B,
                                                  float* __restrict__ C,
                                                  int M, int K, int Nc)
{
    __shared__ float AsT[16][68];   // [k][m]
    __shared__ float Bs[16][68];    // [k][n]
    const int tid = threadIdx.x;
    const int tx = tid & 15, ty = tid >> 4;
    const int bm = blockIdx.y * 64, bn = blockIdx.x * 64;
    float acc[4][4] = {};

    const int ar  = tid >> 2;          // 0..63 : A row within tile
    const int akq = (tid & 3) * 4;     // 0,4,8,12 : k quad
    const int bkr = tid >> 4;          // 0..15 : B k row
    const int bnq = (tid & 15) * 4;    // 0..60 : B col quad

    for (int k0 = 0; k0 < K; k0 += 16) {
        float4 av = make_float4(0.f, 0.f, 0.f, 0.f);
        int m = bm + ar;
        if (m < M) av = *(const float4*)(A + (size_t)m * K + k0 + akq);
        AsT[akq + 0][ar] = av.x;
        AsT[akq + 1][ar] = av.y;
        AsT[akq + 2][ar] = av.z;
        AsT[akq + 3][ar] = av.w;
        float4 bv = *(const float4*)(B + (size_t)(k0 + bkr) * Nc + bn + bnq);
        *(float4*)(&Bs[bkr][bnq]) = bv;
        __syncthreads();
#pragma unroll
        for (int k = 0; k < 16; ++k) {
            float4 a4 = *(const float4*)(&AsT[k][ty * 4]);
            float4 b4 = *(const float4*)(&Bs[k][tx * 4]);
            acc[0][0] += a4.x * b4.x; acc[0][1] += a4.x * b4.y; acc[0][2] += a4.x * b4.z; acc[0][3] += a4.x * b4.w;
            acc[1][0] += a4.y * b4.x; acc[1][1] += a4.y * b4.y; acc[1][2] += a4.y * b4.z; acc[1][3] += a4.y * b4.w;
            acc[2][0] += a4.z * b4.x; acc[2][1] += a4.z * b4.y; acc[2][2] += a4.z * b4.z; acc[2][3] += a4.z * b4.w;
            acc[3][0] += a4.w * b4.x; acc[3][1] += a4.w * b4.y; acc[3][2] += a4.w * b4.z; acc[3][3] += a4.w * b4.w;
        }
        __syncthreads();
    }
#pragma unroll
    for (int i = 0; i < 4; ++i) {
        int m = bm + ty * 4 + i;
        if (m < M) {
#pragma unroll
            for (int j = 0; j < 4; ++j)
                C[(size_t)m * Nc + bn + tx * 4 + j] = acc[i][j];
        }
    }
}

// ---------------- attention scalar products, layer 1: a_src/a_dst [N,4] ----------------
__global__ __launch_bounds__(256) void att1_kernel(const float* __restrict__ h1,
                                                   const float* __restrict__ att_src,
                                                   const float* __restrict__ att_dst,
                                                   float* __restrict__ a_src,
                                                   float* __restrict__ a_dst)
{
    const int wave = threadIdx.x >> 6, lane = threadIdx.x & 63;
    const int n = blockIdx.x * 4 + wave;
    if (n >= N_NODES) return;
    const int h = lane >> 4;
    float4 v = *(const float4*)(h1 + (size_t)n * D1 + lane * 4);
    float4 s4 = *(const float4*)(att_src + lane * 4);
    float4 d4 = *(const float4*)(att_dst + lane * 4);
    float ps = v.x * s4.x + v.y * s4.y + v.z * s4.z + v.w * s4.w;
    float pd = v.x * d4.x + v.y * d4.y + v.z * d4.z + v.w * d4.w;
#pragma unroll
    for (int o = 1; o < 16; o <<= 1) { ps += __shfl_xor(ps, o); pd += __shfl_xor(pd, o); }
    if ((lane & 15) == 0) { a_src[n * 4 + h] = ps; a_dst[n * 4 + h] = pd; }
}

// ---------------- attention scalar products, layer 2: a_src/a_dst [N] ----------------
__global__ __launch_bounds__(256) void att2_kernel(const float* __restrict__ h2,
                                                   const float* __restrict__ att_src,
                                                   const float* __restrict__ att_dst,
                                                   float* __restrict__ a_src,
                                                   float* __restrict__ a_dst)
{
    const int wave = threadIdx.x >> 6, lane = threadIdx.x & 63;
    const int n = blockIdx.x * 4 + wave;
    if (n >= N_NODES) return;
    float v = h2[(size_t)n * HID + lane];
    float ps = v * att_src[lane];
    float pd = v * att_dst[lane];
#pragma unroll
    for (int o = 1; o < 64; o <<= 1) { ps += __shfl_xor(ps, o); pd += __shfl_xor(pd, o); }
    if (lane == 0) { a_src[n] = ps; a_dst[n] = pd; }
}

// ---------------- CSR build: histogram, scan, scatter ----------------
__global__ void edge_hist(const int* __restrict__ ei, int* __restrict__ deg)
{
    for (int e = blockIdx.x * blockDim.x + threadIdx.x; e < E_TOT; e += gridDim.x * blockDim.x) {
        int d = (e < E_EDGES) ? ei[E_EDGES + e] : (e - E_EDGES);
        atomicAdd(&deg[d], 1);
    }
}

__global__ __launch_bounds__(SCAN_B) void scan_block(const int* __restrict__ deg,
                                                     int* __restrict__ incl,
                                                     int* __restrict__ bsum, int n)
{
    __shared__ int s[SCAN_B];
    int i = blockIdx.x * SCAN_B + threadIdx.x;
    int v = (i < n) ? deg[i] : 0;
    s[threadIdx.x] = v;
    __syncthreads();
    for (int off = 1; off < SCAN_B; off <<= 1) {
        int t = (threadIdx.x >= off) ? s[threadIdx.x - off] : 0;
        __syncthreads();
        s[threadIdx.x] += t;
        __syncthreads();
    }
    if (i < n) incl[i] = s[threadIdx.x];
    if (threadIdx.x == SCAN_B - 1) bsum[blockIdx.x] = s[SCAN_B - 1];
}

__global__ void scan_bsum(const int* __restrict__ bsum, int* __restrict__ bex, int nb)
{
    if (threadIdx.x == 0 && blockIdx.x == 0) {
        int run = 0;
        for (int b = 0; b < nb; ++b) { bex[b] = run; run += bsum[b]; }
    }
}

__global__ void finalize_off(const int* __restrict__ deg, const int* __restrict__ incl,
                             const int* __restrict__ bex, int* __restrict__ off,
                             int* __restrict__ cursor, int n)
{
    int i = blockIdx.x * blockDim.x + threadIdx.x;
    if (i < n) { off[i] = incl[i] - deg[i] + bex[i / SCAN_B]; cursor[i] = 0; }
}

__global__ void edge_scatter(const int* __restrict__ ei, const int* __restrict__ off,
                             int* __restrict__ cursor, int* __restrict__ csr_src)
{
    for (int e = blockIdx.x * blockDim.x + threadIdx.x; e < E_TOT; e += gridDim.x * blockDim.x) {
        int s = (e < E_EDGES) ? ei[e] : (e - E_EDGES);
        int d = (e < E_EDGES) ? ei[E_EDGES + e] : (e - E_EDGES);
        int slot = off[d] + atomicAdd(&cursor[d], 1);
        csr_src[slot] = s;
    }
}

// ---------------- layer-1 aggregation: wave per node, fused softmax-norm + b1 + ELU ----------------
__global__ __launch_bounds__(256) void agg1_kernel(const float* __restrict__ h1,
                                                   const int* __restrict__ csr_src,
                                                   const int* __restrict__ off,
                                                   const int* __restrict__ deg,
                                                   const float* __restrict__ a_src,
                                                   const float* __restrict__ a_dst,
                                                   const float* __restrict__ b1,
                                                   float* __restrict__ hE)
{
    const int wave = threadIdx.x >> 6, lane = threadIdx.x & 63;
    const int n = blockIdx.x * 4 + wave;
    if (n >= N_NODES) return;
    const int h = lane >> 4;
    const float adn = a_dst[n * 4 + h];
    const int st = off[n], cnt = deg[n];
    float4 acc = make_float4(0.f, 0.f, 0.f, 0.f);
    float dsum = 0.f;
    int s = csr_src[st];                    // deg >= 1 always (self-loop)
    for (int j = 0; j < cnt; ++j) {
        int s_nxt = (j + 1 < cnt) ? csr_src[st + j + 1] : s;   // prefetch
        float al = a_src[s * 4 + h] + adn;
        al = (al > 0.f) ? al : NEG_SLOPE * al;
        float ex = expf(al);
        dsum += ex;
        float4 v = *(const float4*)(h1 + (size_t)s * D1 + lane * 4);
        acc.x += ex * v.x; acc.y += ex * v.y; acc.z += ex * v.z; acc.w += ex * v.w;
        s = s_nxt;
    }
    const float inv = 1.f / (dsum + 1e-16f);
    float4 bb = *(const float4*)(b1 + lane * 4);
    float4 o;
    o.x = acc.x * inv + bb.x;
    o.y = acc.y * inv + bb.y;
    o.z = acc.z * inv + bb.z;
    o.w = acc.w * inv + bb.w;
    o.x = (o.x > 0.f) ? o.x : expm1f(o.x);
    o.y = (o.y > 0.f) ? o.y : expm1f(o.y);
    o.z = (o.z > 0.f) ? o.z : expm1f(o.z);
    o.w = (o.w > 0.f) ? o.w : expm1f(o.w);
    *(float4*)(hE + (size_t)n * D1 + lane * 4) = o;
}

// ---------------- layer-2 aggregation + register-accumulated mean-pool ----------------
// Each wave owns CHUNK2 consecutive nodes (batch is sorted -> mostly one graph per
// wave) and accumulates the pool contribution in registers, flushing one atomic
// per graph transition. Atomic dword traffic: 6.4M -> ~0.8M, spread over time.
__global__ __launch_bounds__(256) void agg2_pool_kernel(const float* __restrict__ h2,
                                                        const int* __restrict__ csr_src,
                                                        const int* __restrict__ off,
                                                        const int* __restrict__ deg,
                                                        const float* __restrict__ a_src,
                                                        const float* __restrict__ a_dst,
                                                        const float* __restrict__ b2,
                                                        const int* __restrict__ batch,
                                                        float* __restrict__ pool,
                                                        float* __restrict__ cntg)
{
    const int wave = threadIdx.x >> 6, lane = threadIdx.x & 63;
    const int wgid = blockIdx.x * 4 + wave;
    const int n0 = wgid * CHUNK2;
    if (n0 >= N_NODES) return;
    const int n1 = (n0 + CHUNK2 < N_NODES) ? n0 + CHUNK2 : N_NODES;
    const float bb = b2[lane];

    float poolacc = 0.f, ccur = 0.f;
    int gcur = batch[n0];

    for (int n = n0; n < n1; ++n) {
        const float adn = a_dst[n];
        const int st = off[n], cnt = deg[n];
        float acc = 0.f, dsum = 0.f;
        int s = csr_src[st];
        for (int j = 0; j < cnt; ++j) {
            int s_nxt = (j + 1 < cnt) ? csr_src[st + j + 1] : s;   // prefetch
            float al = a_src[s] + adn;
            al = (al > 0.f) ? al : NEG_SLOPE * al;
            float ex = expf(al);
            dsum += ex;
            acc += ex * h2[(size_t)s * HID + lane];
            s = s_nxt;
        }
        float val = acc / (dsum + 1e-16f) + bb;
        int g = batch[n];
        if (g != gcur) {
#if defined(__AMDGCN__)
            unsafeAtomicAdd(&pool[gcur * HID + lane], poolacc);
            if (lane == 0) unsafeAtomicAdd(&cntg[gcur], ccur);
#else
            atomicAdd(&pool[gcur * HID + lane], poolacc);
            if (lane == 0) atomicAdd(&cntg[gcur], ccur);
#endif
            poolacc = 0.f; ccur = 0.f; gcur = g;
        }
        poolacc += val;
        ccur += 1.f;
    }
#if defined(__AMDGCN__)
    unsafeAtomicAdd(&pool[gcur * HID + lane], poolacc);
    if (lane == 0) unsafeAtomicAdd(&cntg[gcur], ccur);
#else
    atomicAdd(&pool[gcur * HID + lane], poolacc);
    if (lane == 0) atomicAdd(&cntg[gcur], ccur);
#endif
}

// ---------------- head: mean, relu MLP, logits ----------------
__global__ void head_kernel(const float* __restrict__ pool, const float* __restrict__ cntg,
                            const float* __restrict__ W3, const float* __restrict__ b3,
                            const float* __restrict__ W4, const float* __restrict__ b4,
                            float* __restrict__ out)
{
    int g = threadIdx.x;
    if (g >= G_GRAPHS) return;
    float invc = 1.f / fmaxf(cntg[g], 1.f);
    float emb[HID];
#pragma unroll
    for (int k = 0; k < HID; ++k) emb[k] = pool[g * HID + k] * invc;
    float z[32];
    for (int j = 0; j < 32; ++j) {
        float s = b3[j];
        for (int k = 0; k < HID; ++k) s += emb[k] * W3[k * 32 + j];
        z[j] = fmaxf(s, 0.f);
    }
    for (int d = 0; d < 2; ++d) {
        float s = b4[d];
        for (int j = 0; j < 32; ++j) s += z[j] * W4[j * 2 + d];
        out[g * 2 + d] = s;
    }
}

extern "C" void kernel_launch(void* const* d_in, const int* in_sizes, int n_in,
                              void* d_out, int out_size, void* d_ws, size_t ws_size,
                              hipStream_t stream)
{
    const float* x     = (const float*)d_in[0];
    const int*   ei    = (const int*)d_in[1];
    const int*   batch = (const int*)d_in[2];
    const float* W1    = (const float*)d_in[3];
    const float* as1w  = (const float*)d_in[4];
    const float* ad1w  = (const float*)d_in[5];
    const float* b1    = (const float*)d_in[6];
    const float* W2    = (const float*)d_in[7];
    const float* as2w  = (const float*)d_in[8];
    const float* ad2w  = (const float*)d_in[9];
    const float* b2    = (const float*)d_in[10];
    const float* W3    = (const float*)d_in[11];
    const float* b3    = (const float*)d_in[12];
    const float* W4    = (const float*)d_in[13];
    const float* b4    = (const float*)d_in[14];
    float* out = (float*)d_out;

    char* ws = (char*)d_ws;
    size_t o = 0;
    auto alloc = [&](size_t bytes) -> void* {
        void* p = ws + o;
        o += (bytes + 255) & ~(size_t)255;
        return p;
    };
    float* h1   = (float*)alloc((size_t)N_NODES * D1 * 4);   // x@W1
    float* hE   = (float*)alloc((size_t)N_NODES * D1 * 4);   // elu(agg1 + b1)
    float* h2   = h1;                                        // alias: h1 dead after agg1
    float* a_s1 = (float*)alloc((size_t)N_NODES * 4 * 4);
    float* a_d1 = (float*)alloc((size_t)N_NODES * 4 * 4);
    float* a_s2 = (float*)alloc((size_t)N_NODES * 4);
    float* a_d2 = (float*)alloc((size_t)N_NODES * 4);
    int*   deg    = (int*)alloc((size_t)N_NODES * 4);
    int*   incl   = (int*)alloc((size_t)N_NODES * 4);
    int*   offv   = (int*)alloc((size_t)N_NODES * 4);
    int*   cursor = (int*)alloc((size_t)N_NODES * 4);
    int*   bsum   = (int*)alloc(128 * 4);
    int*   bex    = (int*)alloc(128 * 4);
    int*   csr    = (int*)alloc((size_t)E_TOT * 4);
    float* pool   = (float*)alloc((size_t)G_GRAPHS * HID * 4);
    float* cntg   = (float*)alloc((size_t)G_GRAPHS * 4);

    hipMemsetAsync(deg, 0, (size_t)N_NODES * 4, stream);
    hipMemsetAsync(pool, 0, (size_t)G_GRAPHS * HID * 4, stream);
    hipMemsetAsync(cntg, 0, (size_t)G_GRAPHS * 4, stream);

    const int nblk_nodes = (N_NODES + 3) / 4;
    const int nscan = (N_NODES + SCAN_B - 1) / SCAN_B;

    // GEMM1: h1 = x @ W1  [100000,256]x[256,256]
    gemm_tiled<<<dim3(D1 / 64, (N_NODES + 63) / 64), 256, 0, stream>>>(x, W1, h1, N_NODES, IN_DIM, D1);
    att1_kernel<<<nblk_nodes, 256, 0, stream>>>(h1, as1w, ad1w, a_s1, a_d1);

    // CSR build (shared by both layers)
    edge_hist<<<4096, 256, 0, stream>>>(ei, deg);
    scan_block<<<nscan, SCAN_B, 0, stream>>>(deg, incl, bsum, N_NODES);
    scan_bsum<<<1, 64, 0, stream>>>(bsum, bex, nscan);
    finalize_off<<<(N_NODES + 255) / 256, 256, 0, stream>>>(deg, incl, bex, offv, cursor, N_NODES);
    edge_scatter<<<4096, 256, 0, stream>>>(ei, offv, cursor, csr);

    // layer-1 gather-aggregate, fused softmax + b1 + ELU
    agg1_kernel<<<nblk_nodes, 256, 0, stream>>>(h1, csr, offv, deg, a_s1, a_d1, b1, hE);

    // GEMM2: h2 = hE @ W2  [100000,256]x[256,64]
    gemm_tiled<<<dim3(HID / 64, (N_NODES + 63) / 64), 256, 0, stream>>>(hE, W2, h2, N_NODES, D1, HID);
    att2_kernel<<<nblk_nodes, 256, 0, stream>>>(h2, as2w, ad2w, a_s2, a_d2);

    // layer-2 gather-aggregate + register-accumulated mean-pool
    const int nwaves2 = (N_NODES + CHUNK2 - 1) / CHUNK2;
    agg2_pool_kernel<<<(nwaves2 + 3) / 4, 256, 0, stream>>>(h2, csr, offv, deg, a_s2, a_d2, b2, batch, pool, cntg);

    // head MLP
    head_kernel<<<1, 64, 0, stream>>>(pool, cntg, W3, b3, W4, b4, out);
}